// Round 6
// baseline (628.191 us; speedup 1.0000x reference)
//
#include <hip/hip_runtime.h>
#include <stdint.h>

#define MTOT  16384   // B*S
#define KDIM  4096    // INTER
#define NDIM  1024    // HID
#define CLIPV 2.5f
#define BK    64
#define NSTEP (KDIM / BK)   // 64

typedef __attribute__((ext_vector_type(4)))  int   i32x4;
typedef __attribute__((ext_vector_type(16))) int   i32x16;
typedef __attribute__((ext_vector_type(16))) float f32x16;
typedef __attribute__((address_space(3))) void lvoid;
typedef __attribute__((address_space(1))) void gvoid;

#define G2L16(g, l) __builtin_amdgcn_global_load_lds((gvoid*)(g), (lvoid*)(l), 16, 0, 0)

// ---------------- max|x| reduction ------------------------------------------------
__global__ __launch_bounds__(256) void maxabs_kernel(
    const float4* __restrict__ x, int n4, unsigned* __restrict__ slot) {
  __shared__ float red[4];
  float m = 0.f;
  const int stride = gridDim.x * blockDim.x;
  for (int i = blockIdx.x * blockDim.x + threadIdx.x; i < n4; i += stride) {
    float4 v = x[i];
    m = fmaxf(m, fmaxf(fmaxf(fabsf(v.x), fabsf(v.y)),
                       fmaxf(fabsf(v.z), fabsf(v.w))));
    if (__any(m >= CLIPV)) break;   // exact: result is CLIP regardless of the rest
  }
  m = fminf(m, CLIPV);
#pragma unroll
  for (int off = 32; off > 0; off >>= 1) m = fmaxf(m, __shfl_xor(m, off));
  if ((threadIdx.x & 63) == 0) red[threadIdx.x >> 6] = m;
  __syncthreads();
  if (threadIdx.x == 0) {
    float bm = fmaxf(fmaxf(red[0], red[1]), fmaxf(red[2], red[3]));
    atomicMax(slot, __float_as_uint(bm));
  }
}

// ---------------- symmetric int8 quantization: q = rint(clip(x)*127/m) ------------
__global__ __launch_bounds__(256) void quant_kernel(
    const float4* __restrict__ x, uint4* __restrict__ q, int n16,
    const unsigned* __restrict__ slot) {
  const float m = fminf(__uint_as_float(*slot), CLIPV);  // m = min(maxabs, clip)
  const float s = 127.0f / m;
  const int stride = gridDim.x * blockDim.x;
  for (int i = blockIdx.x * blockDim.x + threadIdx.x; i < n16; i += stride) {
    const float4* xp = x + 4 * (long)i;
    uint4 o;
    unsigned* op = (unsigned*)&o;
#pragma unroll
    for (int j = 0; j < 4; ++j) {
      float4 v = xp[j];
      int a = (int)rintf(fminf(fmaxf(v.x, -CLIPV), CLIPV) * s);
      int b = (int)rintf(fminf(fmaxf(v.y, -CLIPV), CLIPV) * s);
      int c = (int)rintf(fminf(fmaxf(v.z, -CLIPV), CLIPV) * s);
      int d = (int)rintf(fminf(fmaxf(v.w, -CLIPV), CLIPV) * s);
      op[j] = (unsigned)(a & 255) | ((unsigned)(b & 255) << 8) |
              ((unsigned)(c & 255) << 16) | ((unsigned)(d & 255) << 24);
    }
    q[i] = o;
  }
}

// ---------------- fused int8 GEMM + bias + residual + LayerNorm --------------------
// Block tile 64x1024 (FULL output rows -> LN can fuse). Grid 256 blocks, 1/CU.
// 8 waves, wave tile 64x128 (2x4 MFMA grid of 32x32x32_i8) -> per K-step per wave:
// 12 ds_read_b128 : 16 MFMA (same ratio as the proven 128x256 kernel).
// BK=64, DOUBLE-BUFFERED dynamic LDS: 2 x (4KB A + 64KB B) = 136 KB.
// Counted-vmcnt pipeline (R2-validated sync structure): issue next tile's loads,
// s_waitcnt vmcnt(8), raw s_barrier; never drain to 0 in-loop. With 1 block/CU
// there is no co-resident block, so explicit pipelining is required (m114 inverse).
// LDS swizzle (R2-verified for BK=64): data(row,c) at slot c^((row>>1)&3);
// (4*row + c^((row>>1)&3)) mod 8 is bijective over row mod 8 -> conflict-free.
// Epilogue: y = acc*S + bias + resid in regs; per-row sum/sumsq via 32-lane
// shfl_xor reduce + 4KB LDS cross-wave reduce; normalize; store. The separate
// 128 MB LN pass is eliminated. qW (4MB) is L2-resident per XCD.
__global__ __launch_bounds__(512, 1) void gemm_ln(
    const int8_t* __restrict__ qA, const int8_t* __restrict__ qB,
    float* __restrict__ out, const float* __restrict__ resid,
    const float* __restrict__ bias, const float* __restrict__ gamma,
    const float* __restrict__ beta,
    const unsigned* __restrict__ slot_x, const unsigned* __restrict__ slot_w) {
  extern __shared__ __align__(16) int8_t smem[];   // As[2][4096] | Bs[2][65536]
  int8_t* const As0 = smem;
  int8_t* const Bs0 = smem + 8192;

  const int t  = threadIdx.x;
  const int l  = t & 63;
  const int w  = t >> 6;      // wave id 0..7 (n-direction)
  const int lr = l & 31;
  const int lh = l >> 5;

  const long m0 = (long)blockIdx.x * 64;

  i32x16 acc[2][4] = {};

  // staging pointers. A: 256 slots (4KB), 4 wave-issues -> waves 0..3 only.
  // slot s -> row=s>>2 (4 slots/row), stored col cs=s&3, data col cc=cs^((row>>1)&3)
  const int8_t* gAp = qA;
  if (w < 4) {
    const int s = w * 64 + l, row = s >> 2, cc = (s & 3) ^ ((row >> 1) & 3);
    gAp = qA + (m0 + row) * KDIM + cc * 16;
  }
  // B: 4096 slots (64KB), 8 issues per wave: s = (j*8+w)*64 + l
  const int8_t* gBp[8];
#pragma unroll
  for (int j = 0; j < 8; ++j) {
    const int s = (j * 8 + w) * 64 + l, row = s >> 2, cc = (s & 3) ^ ((row >> 1) & 3);
    gBp[j] = qB + (long)row * KDIM + cc * 16;
  }

  // fragment addresses: addr = base + ((c ^ mask)*16), c = kk*2+lh
  int abase[2], amask[2], bbase[4], bmask[4];
#pragma unroll
  for (int mt = 0; mt < 2; ++mt) {
    const int ra = mt * 32 + lr;             // A row 0..63
    abase[mt] = ra * BK; amask[mt] = (ra >> 1) & 3;
  }
#pragma unroll
  for (int nt = 0; nt < 4; ++nt) {
    const int rb = w * 128 + nt * 32 + lr;   // B row 0..1023
    bbase[nt] = rb * BK; bmask[nt] = (rb >> 1) & 3;
  }

#define STAGE(buf, koff)                                                  \
  do {                                                                    \
    if (w < 4) G2L16(gAp + (koff), As0 + (buf) * 4096 + w * 1024);        \
    _Pragma("unroll")                                                     \
    for (int j = 0; j < 8; ++j)                                           \
      G2L16(gBp[j] + (koff), Bs0 + (buf) * 65536 + (j * 8 + w) * 1024);   \
  } while (0)

  STAGE(0, 0);   // prologue: tile 0 in flight (9 ops waves 0-3, 8 ops waves 4-7)

#pragma unroll 2
  for (int ks = 0; ks < NSTEP; ++ks) {
    const int cur = ks & 1;
    if (ks + 1 < NSTEP) {
      STAGE(cur ^ 1, (ks + 1) * BK);
      // waves 4-7 have exactly 8 outstanding per tile -> vmcnt(8) = current tile
      // landed; waves 0-3 (9/tile) wait one extra next-tile load (harmless).
      asm volatile("s_waitcnt vmcnt(8)" ::: "memory");
    } else {
      asm volatile("s_waitcnt vmcnt(0)" ::: "memory");
    }
    __builtin_amdgcn_s_barrier();
    asm volatile("" ::: "memory");

    const int8_t* A_ = As0 + cur * 4096;
    const int8_t* B_ = Bs0 + cur * 65536;
#pragma unroll
    for (int kk = 0; kk < 2; ++kk) {
      const int c = kk * 2 + lh;
      i32x4 a0 = *(const i32x4*)(A_ + abase[0] + ((c ^ amask[0]) << 4));
      i32x4 a1 = *(const i32x4*)(A_ + abase[1] + ((c ^ amask[1]) << 4));
      i32x4 b0 = *(const i32x4*)(B_ + bbase[0] + ((c ^ bmask[0]) << 4));
      i32x4 b1 = *(const i32x4*)(B_ + bbase[1] + ((c ^ bmask[1]) << 4));
      i32x4 b2 = *(const i32x4*)(B_ + bbase[2] + ((c ^ bmask[2]) << 4));
      i32x4 b3 = *(const i32x4*)(B_ + bbase[3] + ((c ^ bmask[3]) << 4));
      acc[0][0] = __builtin_amdgcn_mfma_i32_32x32x32_i8(a0, b0, acc[0][0], 0, 0, 0);
      acc[1][0] = __builtin_amdgcn_mfma_i32_32x32x32_i8(a1, b0, acc[1][0], 0, 0, 0);
      acc[0][1] = __builtin_amdgcn_mfma_i32_32x32x32_i8(a0, b1, acc[0][1], 0, 0, 0);
      acc[1][1] = __builtin_amdgcn_mfma_i32_32x32x32_i8(a1, b1, acc[1][1], 0, 0, 0);
      acc[0][2] = __builtin_amdgcn_mfma_i32_32x32x32_i8(a0, b2, acc[0][2], 0, 0, 0);
      acc[1][2] = __builtin_amdgcn_mfma_i32_32x32x32_i8(a1, b2, acc[1][2], 0, 0, 0);
      acc[0][3] = __builtin_amdgcn_mfma_i32_32x32x32_i8(a0, b3, acc[0][3], 0, 0, 0);
      acc[1][3] = __builtin_amdgcn_mfma_i32_32x32x32_i8(a1, b3, acc[1][3], 0, 0, 0);
    }
    asm volatile("s_waitcnt lgkmcnt(0)" ::: "memory");   // buf[cur] reads done
    __builtin_amdgcn_s_barrier();                        // safe to overwrite
    asm volatile("" ::: "memory");
  }
#undef STAGE

  // ---------------- epilogue: y = acc*S + bias + resid; rowwise LN ----------------
  const float mx = fminf(__uint_as_float(*slot_x), CLIPV);
  const float mw = fminf(__uint_as_float(*slot_w), CLIPV);
  const float S  = mx * mw * (1.0f / (127.0f * 127.0f));

  const int coln = w * 128 + lr;   // this lane's col base (block spans all 1024 cols)
  float bia[4], gam[4], bet[4];
#pragma unroll
  for (int nt = 0; nt < 4; ++nt) {
    bia[nt] = bias[coln + nt * 32];
    gam[nt] = gamma[coln + nt * 32];
    bet[nt] = beta[coln + nt * 32];
  }

  // C/D layout (32x32): col=lane&31, row=(r&3)+8*(r>>2)+4*lh
  f32x16 yf[2][4];
#pragma unroll
  for (int mt = 0; mt < 2; ++mt)
#pragma unroll
    for (int nt = 0; nt < 4; ++nt)
#pragma unroll
      for (int r = 0; r < 16; ++r) {
        const int lrow = mt * 32 + (r & 3) + 8 * (r >> 2) + 4 * lh;
        yf[mt][nt][r] = (float)acc[mt][nt][r] * S + bia[nt]
                      + resid[(m0 + lrow) * NDIM + coln + nt * 32];
      }

  // per-row sum/sumsq: 32-lane shfl reduce (half-wave = one row), then LDS
  // cross-wave reduce. red[64 rows][8 waves][2] floats = 4KB, reuses As area
  // (all LDS reads drained at the final lgkmcnt(0)+barrier above).
  float* red = (float*)smem;
#pragma unroll
  for (int mt = 0; mt < 2; ++mt)
#pragma unroll
    for (int r = 0; r < 16; ++r) {
      const int lrow = mt * 32 + (r & 3) + 8 * (r >> 2) + 4 * lh;
      float s1 = 0.f, s2 = 0.f;
#pragma unroll
      for (int nt = 0; nt < 4; ++nt) {
        const float v = yf[mt][nt][r];
        s1 += v; s2 += v * v;
      }
#pragma unroll
      for (int off = 16; off > 0; off >>= 1) {
        s1 += __shfl_xor(s1, off);
        s2 += __shfl_xor(s2, off);
      }
      if (lr == 0) { red[lrow * 16 + w * 2] = s1; red[lrow * 16 + w * 2 + 1] = s2; }
    }
  __syncthreads();

#pragma unroll
  for (int mt = 0; mt < 2; ++mt)
#pragma unroll
    for (int r = 0; r < 16; ++r) {
      const int lrow = mt * 32 + (r & 3) + 8 * (r >> 2) + 4 * lh;
      float s1 = 0.f, s2 = 0.f;
#pragma unroll
      for (int g = 0; g < 8; ++g) {
        s1 += red[lrow * 16 + g * 2];
        s2 += red[lrow * 16 + g * 2 + 1];
      }
      const float mu   = s1 * (1.0f / NDIM);
      const float var  = s2 * (1.0f / NDIM) - mu * mu;
      const float rstd = rsqrtf(var + 1e-12f);
      float* orow = out + (m0 + lrow) * NDIM + coln;
#pragma unroll
      for (int nt = 0; nt < 4; ++nt)
        orow[nt * 32] = gam[nt] * (yf[mt][nt][r] - mu) * rstd + bet[nt];
    }
}

extern "C" void kernel_launch(void* const* d_in, const int* in_sizes, int n_in,
                              void* d_out, int out_size, void* d_ws,
                              size_t ws_size, hipStream_t stream) {
  const float* x     = (const float*)d_in[0];  // hidden_states [4,4096,4096]
  const float* resid = (const float*)d_in[1];  // input_tensor  [4,4096,1024]
  const float* W     = (const float*)d_in[2];  // [1024,4096]
  const float* b     = (const float*)d_in[3];
  const float* gamma = (const float*)d_in[4];
  const float* beta  = (const float*)d_in[5];
  float* out = (float*)d_out;

  // ws layout: qA 64MB | qW 4MB | 2 uint max-slots  (~68MB total)
  int8_t* qA = (int8_t*)d_ws;
  int8_t* qW = qA + (size_t)MTOT * KDIM;
  unsigned* slots = (unsigned*)(qW + (size_t)NDIM * KDIM);

  hipMemsetAsync(slots, 0, 8, stream);
  maxabs_kernel<<<2048, 256, 0, stream>>>((const float4*)x, MTOT * KDIM / 4, slots);
  maxabs_kernel<<<512, 256, 0, stream>>>((const float4*)W, NDIM * KDIM / 4, slots + 1);
  quant_kernel<<<2048, 256, 0, stream>>>((const float4*)x, (uint4*)qA,
                                         MTOT * KDIM / 16, slots);
  quant_kernel<<<512, 256, 0, stream>>>((const float4*)W, (uint4*)qW,
                                        NDIM * KDIM / 16, slots + 1);
  gemm_ln<<<MTOT / 64, 512, 2 * 4096 + 2 * 65536, stream>>>(
      qA, qW, out, resid, b, gamma, beta, slots, slots + 1);
}

// Round 7
// 553.763 us; speedup vs baseline: 1.1344x; 1.1344x over previous
//
#include <hip/hip_runtime.h>
#include <stdint.h>

#define MTOT  16384   // B*S
#define KDIM  4096    // INTER
#define NDIM  1024    // HID
#define CLIPV 2.5f

typedef __attribute__((ext_vector_type(4)))  int i32x4;
typedef __attribute__((ext_vector_type(16))) int i32x16;
typedef __attribute__((address_space(3))) void lvoid;
typedef __attribute__((address_space(1))) void gvoid;

#define G2L16(g, l) __builtin_amdgcn_global_load_lds((gvoid*)(g), (lvoid*)(l), 16, 0, 0)

// round-to-nearest-even f32 -> bf16
__device__ __forceinline__ unsigned short f2bf(float f) {
  unsigned u = __float_as_uint(f);
  return (unsigned short)((u + 0x7FFFu + ((u >> 16) & 1u)) >> 16);
}

// ---------------- max|x| reduction ------------------------------------------------
// m = max|clip(x,±2.5)| = min(max|x|, 2.5). Once any lane has seen |x| >= CLIP the
// wave's contribution is exactly CLIP -> stop reading (exact). Block-reduce ->
// ONE atomic per block.
__global__ __launch_bounds__(256) void maxabs_kernel(
    const float4* __restrict__ x, int n4, unsigned* __restrict__ slot) {
  __shared__ float red[4];
  float m = 0.f;
  const int stride = gridDim.x * blockDim.x;
  for (int i = blockIdx.x * blockDim.x + threadIdx.x; i < n4; i += stride) {
    float4 v = x[i];
    m = fmaxf(m, fmaxf(fmaxf(fabsf(v.x), fabsf(v.y)),
                       fmaxf(fabsf(v.z), fabsf(v.w))));
    if (__any(m >= CLIPV)) break;   // exact: result is CLIP regardless of the rest
  }
  m = fminf(m, CLIPV);
#pragma unroll
  for (int off = 32; off > 0; off >>= 1) m = fmaxf(m, __shfl_xor(m, off));
  if ((threadIdx.x & 63) == 0) red[threadIdx.x >> 6] = m;
  __syncthreads();
  if (threadIdx.x == 0) {
    float bm = fmaxf(fmaxf(red[0], red[1]), fmaxf(red[2], red[3]));
    atomicMax(slot, __float_as_uint(bm));
  }
}

// ---------------- symmetric int8 quantization: q = rint(clip(x)*127/m) ------------
// 64 B in / 16 B out per thread per iteration (uint4 stores).
__global__ __launch_bounds__(256) void quant_kernel(
    const float4* __restrict__ x, uint4* __restrict__ q, int n16,
    const unsigned* __restrict__ slot) {
  const float m = fminf(__uint_as_float(*slot), CLIPV);  // m = min(maxabs, clip)
  const float s = 127.0f / m;
  const int stride = gridDim.x * blockDim.x;
  for (int i = blockIdx.x * blockDim.x + threadIdx.x; i < n16; i += stride) {
    const float4* xp = x + 4 * (long)i;
    uint4 o;
    unsigned* op = (unsigned*)&o;
#pragma unroll
    for (int j = 0; j < 4; ++j) {
      float4 v = xp[j];
      int a = (int)rintf(fminf(fmaxf(v.x, -CLIPV), CLIPV) * s);
      int b = (int)rintf(fminf(fmaxf(v.y, -CLIPV), CLIPV) * s);
      int c = (int)rintf(fminf(fmaxf(v.z, -CLIPV), CLIPV) * s);
      int d = (int)rintf(fminf(fmaxf(v.w, -CLIPV), CLIPV) * s);
      op[j] = (unsigned)(a & 255) | ((unsigned)(b & 255) << 8) |
              ((unsigned)(c & 255) << 16) | ((unsigned)(d & 255) << 24);
    }
    q[i] = o;
  }
}

// ---------------- int8 GEMM: y = bf16(S*acc + bias + resid) ------------------------
// PROVEN core (561.8 µs R5): block tile 128x256, BK=128, 2-phase
// stage->syncthreads->compute->syncthreads. 4 waves in 2x2; wave tile 64x128
// (2x4 MFMA grid of mfma_i32_32x32x32_i8). Per kk: 6 ds_read_b128 feed 8 MFMAs.
// LDS 16B slots XOR-swizzled within each 128B row: data(row,c) at row*8+(c^(row&7)).
// __launch_bounds__(256,2) -> 2 blocks/CU (48KB LDS each); co-resident block hides
// the vmcnt(0)+barrier drain (m114). R6's 1-block/CU fused-LN variant serialized
// (MfmaUtil 15%) -> reverted; LN stays a separate kernel, linked via bf16 y (32MB).
// XCD remap: b=blockIdx.x+4*blockIdx.y; ytile=b&127, xtile=b>>7 puts the 4 n-tile
// siblings of one A-panel on the same XCD (b == ytile mod 8).
__global__ __launch_bounds__(256, 2) void gemm_i8(
    const int8_t* __restrict__ qA, const int8_t* __restrict__ qB,
    unsigned short* __restrict__ y, const float* __restrict__ resid,
    const float* __restrict__ bias,
    const unsigned* __restrict__ slot_x, const unsigned* __restrict__ slot_w) {
  __shared__ __align__(16) int8_t As[128 * 128];   // 16 KB
  __shared__ __align__(16) int8_t Bs[256 * 128];   // 32 KB

  const int t  = threadIdx.x;
  const int l  = t & 63;
  const int w  = t >> 6;
  const int wm = (w & 1) * 64;    // wave m-offset
  const int wn = (w >> 1) * 128;  // wave n-offset
  const int lr = l & 31;          // m/n index within 32-tile
  const int lh = l >> 5;          // k-chunk half

  const int b = blockIdx.x + 4 * blockIdx.y;  // HW dispatch-linear id
  const long m0 = (long)(b & 127) * 128;      // ytile
  const long n0 = (long)(b >> 7) * 256;       // xtile

  i32x16 acc[2][4] = {};

  // staging pointers: slot s covers (row=s>>3, stored col=s&7 -> data col (s&7)^(row&7))
  const int8_t* gA[4];
  const int8_t* gB[8];
#pragma unroll
  for (int j = 0; j < 4; ++j) {
    const int s = t + 256 * j, row = s >> 3, cc = (s & 7) ^ (row & 7);
    gA[j] = qA + (m0 + row) * KDIM + cc * 16;
  }
#pragma unroll
  for (int j = 0; j < 8; ++j) {
    const int s = t + 256 * j, row = s >> 3, cc = (s & 7) ^ (row & 7);
    gB[j] = qB + (n0 + row) * KDIM + cc * 16;
  }
  const int ldsb = (t & 192) * 16;  // wave-uniform: w*1024 (+ j*4096 per issue)

  // fragment address prep (per-lane): addr = base + ((kk*2+lh) ^ mask)*16
  int abase[2], amask[2], bbase[4], bmask[4];
#pragma unroll
  for (int mt = 0; mt < 2; ++mt) {
    const int ra = wm + mt * 32 + lr;
    abase[mt] = ra * 128; amask[mt] = ra & 7;
  }
#pragma unroll
  for (int nt = 0; nt < 4; ++nt) {
    const int rb = wn + nt * 32 + lr;
    bbase[nt] = rb * 128; bmask[nt] = rb & 7;
  }

  for (int k0 = 0; k0 < KDIM; k0 += 128) {
#pragma unroll
    for (int j = 0; j < 4; ++j) G2L16(gA[j] + k0, As + ldsb + j * 4096);
#pragma unroll
    for (int j = 0; j < 8; ++j) G2L16(gB[j] + k0, Bs + ldsb + j * 4096);
    __syncthreads();
#pragma unroll
    for (int kk = 0; kk < 4; ++kk) {
      const int c = kk * 2 + lh;
      i32x4 a0 = *(const i32x4*)(As + abase[0] + ((c ^ amask[0]) << 4));
      i32x4 a1 = *(const i32x4*)(As + abase[1] + ((c ^ amask[1]) << 4));
      i32x4 b0 = *(const i32x4*)(Bs + bbase[0] + ((c ^ bmask[0]) << 4));
      i32x4 b1 = *(const i32x4*)(Bs + bbase[1] + ((c ^ bmask[1]) << 4));
      i32x4 b2 = *(const i32x4*)(Bs + bbase[2] + ((c ^ bmask[2]) << 4));
      i32x4 b3 = *(const i32x4*)(Bs + bbase[3] + ((c ^ bmask[3]) << 4));
      acc[0][0] = __builtin_amdgcn_mfma_i32_32x32x32_i8(a0, b0, acc[0][0], 0, 0, 0);
      acc[1][0] = __builtin_amdgcn_mfma_i32_32x32x32_i8(a1, b0, acc[1][0], 0, 0, 0);
      acc[0][1] = __builtin_amdgcn_mfma_i32_32x32x32_i8(a0, b1, acc[0][1], 0, 0, 0);
      acc[1][1] = __builtin_amdgcn_mfma_i32_32x32x32_i8(a1, b1, acc[1][1], 0, 0, 0);
      acc[0][2] = __builtin_amdgcn_mfma_i32_32x32x32_i8(a0, b2, acc[0][2], 0, 0, 0);
      acc[1][2] = __builtin_amdgcn_mfma_i32_32x32x32_i8(a1, b2, acc[1][2], 0, 0, 0);
      acc[0][3] = __builtin_amdgcn_mfma_i32_32x32x32_i8(a0, b3, acc[0][3], 0, 0, 0);
      acc[1][3] = __builtin_amdgcn_mfma_i32_32x32x32_i8(a1, b3, acc[1][3], 0, 0, 0);
    }
    __syncthreads();
  }

  const float mx = fminf(__uint_as_float(*slot_x), CLIPV);
  const float mw = fminf(__uint_as_float(*slot_w), CLIPV);
  const float S  = mx * mw * (1.0f / (127.0f * 127.0f));

  // C/D layout (32x32, dtype-independent): col=lane&31, row=(r&3)+8*(r>>2)+4*(lane>>5)
  const int coln = (int)n0 + wn + lr;
  float bv[4];
#pragma unroll
  for (int nt = 0; nt < 4; ++nt) bv[nt] = bias[coln + nt * 32];

#pragma unroll
  for (int mt = 0; mt < 2; ++mt)
#pragma unroll
    for (int r = 0; r < 16; ++r) {
      const long row = m0 + wm + mt * 32 + (r & 3) + 8 * (r >> 2) + 4 * lh;
      unsigned short* yrow = y + row * NDIM + coln;
      const float* rrow = resid + row * NDIM + coln;
#pragma unroll
      for (int nt = 0; nt < 4; ++nt)
        yrow[nt * 32] = f2bf((float)acc[mt][nt][r] * S + bv[nt] + rrow[nt * 32]);
    }
}

// ---------------- LayerNorm: out = gamma*(y-mu)*rstd + beta, y in bf16 -------------
// One wave per row; lane reads 2 uint4 (16 bf16) at lane+64*j -> 1024 elems/row.
// No LDS, no __syncthreads.
__global__ __launch_bounds__(256) void ln_kernel(
    const unsigned short* __restrict__ yb, float* __restrict__ out,
    const float* __restrict__ gamma, const float* __restrict__ beta) {
  const int lane = threadIdx.x & 63;
  const long row = (long)blockIdx.x * 4 + (threadIdx.x >> 6);
  const uint4* yp = (const uint4*)(yb + row * NDIM);
  float v[2][8];
  float sum = 0.f, ss = 0.f;
#pragma unroll
  for (int j = 0; j < 2; ++j) {
    uint4 u = yp[lane + 64 * j];
    const unsigned* up = (const unsigned*)&u;
#pragma unroll
    for (int e = 0; e < 4; ++e) {
      const float lo = __uint_as_float(up[e] << 16);
      const float hi = __uint_as_float(up[e] & 0xFFFF0000u);
      v[j][2 * e]     = lo;
      v[j][2 * e + 1] = hi;
      sum += lo + hi;
      ss  += lo * lo + hi * hi;
    }
  }
#pragma unroll
  for (int off = 32; off > 0; off >>= 1) {
    sum += __shfl_xor(sum, off);
    ss  += __shfl_xor(ss, off);
  }
  const float mu   = sum * (1.0f / NDIM);
  const float var  = ss * (1.0f / NDIM) - mu * mu;
  const float rstd = rsqrtf(var + 1e-12f);
#pragma unroll
  for (int j = 0; j < 2; ++j) {
    const int cb = (lane + 64 * j) * 8;   // col base, 32B-aligned
    const float4* gp = (const float4*)(gamma + cb);
    const float4* bp = (const float4*)(beta + cb);
    float* orow = out + row * NDIM + cb;
#pragma unroll
    for (int h = 0; h < 2; ++h) {
      float4 g = gp[h], be = bp[h], o;
      o.x = g.x * (v[j][4 * h]     - mu) * rstd + be.x;
      o.y = g.y * (v[j][4 * h + 1] - mu) * rstd + be.y;
      o.z = g.z * (v[j][4 * h + 2] - mu) * rstd + be.z;
      o.w = g.w * (v[j][4 * h + 3] - mu) * rstd + be.w;
      *(float4*)(orow + 4 * h) = o;
    }
  }
}

extern "C" void kernel_launch(void* const* d_in, const int* in_sizes, int n_in,
                              void* d_out, int out_size, void* d_ws,
                              size_t ws_size, hipStream_t stream) {
  const float* x     = (const float*)d_in[0];  // hidden_states [4,4096,4096]
  const float* resid = (const float*)d_in[1];  // input_tensor  [4,4096,1024]
  const float* W     = (const float*)d_in[2];  // [1024,4096]
  const float* b     = (const float*)d_in[3];
  const float* gamma = (const float*)d_in[4];
  const float* beta  = (const float*)d_in[5];
  float* out = (float*)d_out;

  // ws layout: qA 64MB | qW 4MB | slots (256B pad) | y_bf16 32MB  (~100MB total)
  int8_t* qA = (int8_t*)d_ws;
  int8_t* qW = qA + (size_t)MTOT * KDIM;
  unsigned* slots = (unsigned*)(qW + (size_t)NDIM * KDIM);
  unsigned short* ybf = (unsigned short*)((int8_t*)slots + 256);

  hipMemsetAsync(slots, 0, 8, stream);
  maxabs_kernel<<<2048, 256, 0, stream>>>((const float4*)x, MTOT * KDIM / 4, slots);
  maxabs_kernel<<<512, 256, 0, stream>>>((const float4*)W, NDIM * KDIM / 4, slots + 1);
  quant_kernel<<<2048, 256, 0, stream>>>((const float4*)x, (uint4*)qA,
                                         MTOT * KDIM / 16, slots);
  quant_kernel<<<512, 256, 0, stream>>>((const float4*)W, (uint4*)qW,
                                        NDIM * KDIM / 16, slots + 1);
  gemm_i8<<<dim3(NDIM / 256, MTOT / 128), 256, 0, stream>>>(qA, qW, ybf, resid, b,
                                                            slots, slots + 1);
  ln_kernel<<<MTOT / 4, 256, 0, stream>>>(ybf, out, gamma, beta);
}